// Round 19
// baseline (287.981 us; speedup 1.0000x reference)
//
#include <hip/hip_runtime.h>
#include <hip/hip_bf16.h>
#include <math.h>

// Problem constants
#define B_ 256
#define S_ 24
#define N_ 207
#define U_ 64
#define A_ 256
#define H_ (N_*U_)          // 13248
#define H2_ (2*H_)          // 26496
#define BS_ (B_*S_)         // 6144
#define NF_ 129             // 1 + 2U
#define FP_ 192             // padded feature width of MB rows
#define KP_ 256             // padded node count (K of adj GEMMs)
#define MR_ 6400            // unified attention rows: 6144 enc + 256 hid
#define ZSPL_ 9             // split-K partials

typedef __attribute__((ext_vector_type(8))) short bf16x8;
typedef __attribute__((ext_vector_type(4))) float f32x4;

#define GAS __attribute__((address_space(1)))
#define LAS __attribute__((address_space(3)))

static __device__ __forceinline__ void gload16(const __hip_bfloat16* g, void* lds) {
    __builtin_amdgcn_global_load_lds((const GAS uint32_t*)g, (LAS uint32_t*)lds, 16, 0, 0);
}

// ---------------------------------------------------------------------------
// bf16 MFMA GEMM template (R8-R18-validated core). C = A[M,K] @ BT[N,K]^T.
// EPI: 2 = bf16 store; 3 = bf16 remap (rh cols); 4 = sigmoid store;
//      5 = GRU epilogue + FUSED output projection (BN=64 required).
// ---------------------------------------------------------------------------
template<int BM, int BN, int EPI>
__global__ __launch_bounds__(256)
void mfma_gemm(const __hip_bfloat16* __restrict__ A, int lda,
               const __hip_bfloat16* __restrict__ BT, int ldb,
               void* __restrict__ Cv, int ldc,
               int kchunk, int niter,
               const float* __restrict__ ep0,
               const float* __restrict__ ep1,
               const float* __restrict__ ep2,
               const float* __restrict__ e_wt,
               const float* __restrict__ e_pw,
               const float* __restrict__ e_pb,
               const float* __restrict__ e_in,
               float* __restrict__ e_o0)
{
    constexpr int FM = BM / 32, FN = BN / 32;
    __shared__ __align__(128) char smem[(BM + BN) * 128];
    char* As = smem;
    char* Bs = smem + BM * 128;

    const int tid  = threadIdx.x;
    const int lane = tid & 63;
    const int wid  = tid >> 6;
    const int wr   = wid >> 1, wc = wid & 1;

    const int n0 = blockIdx.x * BN;
    const int m0 = blockIdx.y * BM;
    const long k0 = (long)blockIdx.z * kchunk;

    const int qk = lane >> 4;
    const int fr = lane & 15;
    const int sw = (lane & 7) << 4;

    f32x4 acc[FM][FN] = {};

    for (int it = 0; it < niter; ++it) {
        const long kb = k0 + (long)it * 64;
        #pragma unroll
        for (int p = 0; p < BM / 32; ++p) {
            const int chunk = p * 4 + wid;
            const int blk   = chunk * 64 + lane;
            const int r     = blk >> 3;
            const int klog  = ((blk & 7) << 4) ^ ((r & 7) << 4);
            gload16(A + (size_t)(m0 + r) * lda + kb + (klog >> 1), As + chunk * 1024);
        }
        #pragma unroll
        for (int p = 0; p < BN / 32; ++p) {
            const int chunk = p * 4 + wid;
            const int blk   = chunk * 64 + lane;
            const int r     = blk >> 3;
            const int klog  = ((blk & 7) << 4) ^ ((r & 7) << 4);
            gload16(BT + (size_t)(n0 + r) * ldb + kb + (klog >> 1), Bs + chunk * 1024);
        }
        __syncthreads();
        #pragma unroll
        for (int ks = 0; ks < 2; ++ks) {
            const int ko = ks * 64 + qk * 16;
            bf16x8 a[FM], b[FN];
            #pragma unroll
            for (int i = 0; i < FM; ++i)
                a[i] = *(const bf16x8*)(As + (wr * (BM/2) + i * 16 + fr) * 128 + (ko ^ sw));
            #pragma unroll
            for (int j = 0; j < FN; ++j)
                b[j] = *(const bf16x8*)(Bs + (wc * (BN/2) + j * 16 + fr) * 128 + (ko ^ sw));
            #pragma unroll
            for (int i = 0; i < FM; ++i)
                #pragma unroll
                for (int j = 0; j < FN; ++j)
                    acc[i][j] = __builtin_amdgcn_mfma_f32_16x16x32_bf16(a[i], b[j], acc[i][j], 0, 0, 0);
        }
        __syncthreads();
    }

    // EPI=5 projection reduction buffer (aliases LDS, dead after last sync)
    float* rsum = (float*)smem;
    if (EPI == 5) {
        if (tid < BM) rsum[tid] = 0.f;
        __syncthreads();
    }
    float tpart[FM][4];
    if (EPI == 5) {
        #pragma unroll
        for (int mi = 0; mi < FM; ++mi)
            #pragma unroll
            for (int q = 0; q < 4; ++q) tpart[mi][q] = 0.f;
    }

    // C/D layout: col=lane&15, row=(lane>>4)*4+reg  [m89-verified]
    #pragma unroll
    for (int mi = 0; mi < FM; ++mi)
        #pragma unroll
        for (int ni = 0; ni < FN; ++ni) {
            const int rbase = m0 + wr * (BM/2) + mi * 16 + qk * 4;
            const int col   = n0 + wc * (BN/2) + ni * 16 + fr;
            #pragma unroll
            for (int q = 0; q < 4; ++q) {
                const int row = rbase + q;
                const float v = acc[mi][ni][q];
                if (EPI == 2) {
                    ((__hip_bfloat16*)Cv)[(size_t)row * ldc + col] = __float2bfloat16(v);
                } else if (EPI == 3) {
                    const int bb = col >> 6, uu = col & 63;
                    ((__hip_bfloat16*)Cv)[((size_t)row * 256 + bb) * FP_ + 65 + uu] = __float2bfloat16(v);
                } else if (EPI == 4) {
                    float sv = v + ep0[col];
                    ((float*)Cv)[(size_t)row * ldc + col] = 1.f / (1.f + expf(-sv));
                } else { // EPI == 5
                    const int nn = row >> 8, bb = row & 255;
                    float cg = tanhf(v + ep0[col]);
                    float ug = ep1[(size_t)row * 128 + 64 + col];
                    const size_t hoff = (size_t)bb * H_ + nn * U_ + col;
                    float nh = ug * ep2[hoff] + (1.f - ug) * cg;
                    ((float*)Cv)[hoff] = nh;
                    tpart[mi][q] += nh * e_pw[col] + e_wt[hoff] * e_pw[64 + col];
                }
            }
        }

    if (EPI == 5) {
        #pragma unroll
        for (int mi = 0; mi < FM; ++mi)
            #pragma unroll
            for (int q = 0; q < 4; ++q) {
                float t = tpart[mi][q];
                #pragma unroll
                for (int off = 8; off; off >>= 1) t += __shfl_xor(t, off, 16);
                if (fr == 0) {
                    const int rloc = wr * (BM/2) + mi * 16 + qk * 4 + q;
                    atomicAdd(&rsum[rloc], t);   // LDS atomic — cheap
                }
            }
        __syncthreads();
        if (tid < BM) {
            const int row = m0 + tid;
            const int nn = row >> 8, bb = row & 255;
            e_o0[bb * N_ + nn] = rsum[tid] + e_in[bb * N_ + nn] * e_pw[128] + e_pb[0];
        }
    }
}

// ---------------------------------------------------------------------------
// Fused attention GEMM — R16 dbuf structure, BN=128 for occupancy:
// LDS 2x(8KB A + 16KB B) = 48KB -> 3 blocks/CU (was 80KB -> 2).
// grid (2,100,9) = 1800 blocks; x-blocks share the A panel (2nd read L2-hot).
// (R14's "occupancy doesn't help" was measured with the atomic serializer
// masking it; post-R15 the kernel is stall-bound so TLP should pay.)
// ---------------------------------------------------------------------------
__global__ __launch_bounds__(256)
void gemm_enchid(const float* __restrict__ Aenc,
                 const float* __restrict__ Ahid,
                 const __hip_bfloat16* __restrict__ WTBF,
                 float* __restrict__ Pz,
                 int kchunk, int niter)
{
    __shared__ __align__(128) char smem[2 * (64 + 128) * 128];   // 48 KB

    const int tid  = threadIdx.x;
    const int lane = tid & 63;
    const int wid  = tid >> 6;
    const int wr   = wid >> 1, wc = wid & 1;

    const bool isH = (blockIdx.y >= 96);
    const float* A = isH ? Ahid : Aenc;
    const int lm0  = (isH ? (blockIdx.y - 96) : blockIdx.y) * 64;
    const int gm0  = (isH ? 6144 : 0) + lm0;
    const int n0   = blockIdx.x * 128;
    const __hip_bfloat16* BT = WTBF + (isH ? 0 : H_);

    const long k0 = (long)blockIdx.z * kchunk;

    const int qk = lane >> 4;
    const int fr = lane & 15;
    const int sw = (lane & 7) << 4;

    int arow[2], akc[2];
    #pragma unroll
    for (int h = 0; h < 2; ++h) {
        const int c = h * 256 + tid;
        arow[h] = c >> 3;
        akc[h]  = c & 7;
    }

    f32x4 acc[2][4] = {};
    float4 pfx[2], pfy[2];

    // ---- prologue: stage tile 0 into buf0 ----
    {
        const long kb = k0;
        #pragma unroll
        for (int p = 0; p < 4; ++p) {          // B: 128 rows x 128B = 16 chunks
            const int chunk = p * 4 + wid;
            const int blk   = chunk * 64 + lane;
            const int r     = blk >> 3;
            const int klog  = ((blk & 7) << 4) ^ ((r & 7) << 4);
            gload16(BT + (size_t)(n0 + r) * H2_ + kb + (klog >> 1), smem + 8192 + chunk * 1024);
        }
        #pragma unroll
        for (int h = 0; h < 2; ++h) {
            const float* src = A + (size_t)(lm0 + arow[h]) * H_ + kb + akc[h] * 8;
            pfx[h] = *(const float4*)(src);
            pfy[h] = *(const float4*)(src + 4);
        }
        #pragma unroll
        for (int h = 0; h < 2; ++h) {
            union { __hip_bfloat16 hh[8]; int4 u; } pk;
            pk.hh[0] = __float2bfloat16(pfx[h].x); pk.hh[1] = __float2bfloat16(pfx[h].y);
            pk.hh[2] = __float2bfloat16(pfx[h].z); pk.hh[3] = __float2bfloat16(pfx[h].w);
            pk.hh[4] = __float2bfloat16(pfy[h].x); pk.hh[5] = __float2bfloat16(pfy[h].y);
            pk.hh[6] = __float2bfloat16(pfy[h].z); pk.hh[7] = __float2bfloat16(pfy[h].w);
            *(int4*)(smem + arow[h] * 128 + ((akc[h] << 4) ^ ((arow[h] & 7) << 4))) = pk.u;
        }
        __syncthreads();
    }

    int cur = 0;
    for (int it = 0; it < niter; ++it) {
        char* curbuf = smem + cur * 24576;
        char* altbuf = smem + (cur ^ 1) * 24576;
        const bool pf = (it + 1 < niter);
        const long kbn = k0 + (long)(it + 1) * 64;

        if (pf) {
            #pragma unroll
            for (int p = 0; p < 4; ++p) {
                const int chunk = p * 4 + wid;
                const int blk   = chunk * 64 + lane;
                const int r     = blk >> 3;
                const int klog  = ((blk & 7) << 4) ^ ((r & 7) << 4);
                gload16(BT + (size_t)(n0 + r) * H2_ + kbn + (klog >> 1), altbuf + 8192 + chunk * 1024);
            }
            #pragma unroll
            for (int h = 0; h < 2; ++h) {
                const float* src = A + (size_t)(lm0 + arow[h]) * H_ + kbn + akc[h] * 8;
                pfx[h] = *(const float4*)(src);
                pfy[h] = *(const float4*)(src + 4);
            }
        }

        #pragma unroll
        for (int ks = 0; ks < 2; ++ks) {
            const int ko = ks * 64 + qk * 16;
            bf16x8 a[2], b[4];
            #pragma unroll
            for (int i = 0; i < 2; ++i)
                a[i] = *(const bf16x8*)(curbuf + (wr * 32 + i * 16 + fr) * 128 + (ko ^ sw));
            #pragma unroll
            for (int j = 0; j < 4; ++j)
                b[j] = *(const bf16x8*)(curbuf + 8192 + (wc * 64 + j * 16 + fr) * 128 + (ko ^ sw));
            #pragma unroll
            for (int i = 0; i < 2; ++i)
                #pragma unroll
                for (int j = 0; j < 4; ++j)
                    acc[i][j] = __builtin_amdgcn_mfma_f32_16x16x32_bf16(a[i], b[j], acc[i][j], 0, 0, 0);
        }

        if (pf) {
            #pragma unroll
            for (int h = 0; h < 2; ++h) {
                union { __hip_bfloat16 hh[8]; int4 u; } pk;
                pk.hh[0] = __float2bfloat16(pfx[h].x); pk.hh[1] = __float2bfloat16(pfx[h].y);
                pk.hh[2] = __float2bfloat16(pfx[h].z); pk.hh[3] = __float2bfloat16(pfx[h].w);
                pk.hh[4] = __float2bfloat16(pfy[h].x); pk.hh[5] = __float2bfloat16(pfy[h].y);
                pk.hh[6] = __float2bfloat16(pfy[h].z); pk.hh[7] = __float2bfloat16(pfy[h].w);
                *(int4*)(altbuf + arow[h] * 128 + ((akc[h] << 4) ^ ((arow[h] & 7) << 4))) = pk.u;
            }
        }
        __syncthreads();
        cur ^= 1;
    }

    float* Pzs = Pz + (size_t)blockIdx.z * MR_ * A_;
    #pragma unroll
    for (int mi = 0; mi < 2; ++mi)
        #pragma unroll
        for (int ni = 0; ni < 4; ++ni) {
            const int rbase = gm0 + wr * 32 + mi * 16 + qk * 4;
            const int col   = n0 + wc * 64 + ni * 16 + fr;
            #pragma unroll
            for (int q = 0; q < 4; ++q)
                Pzs[(size_t)(rbase + q) * A_ + col] = acc[mi][ni][q];
        }
}

// attn_W (2H, 256) fp32 -> WT_BF (256, 2H) bf16, 32x32 LDS tiles
__global__ __launch_bounds__(256)
void transpose_cvt_kernel(const float* __restrict__ in, __hip_bfloat16* __restrict__ out) {
    __shared__ float tile[32][33];
    const int h0 = blockIdx.x * 32, a0 = blockIdx.y * 32;
    const int tx = threadIdx.x & 31, ty4 = threadIdx.x >> 5;
    #pragma unroll
    for (int i = 0; i < 4; ++i) {
        int r = ty4 * 4 + i;
        tile[r][tx] = in[(size_t)(h0 + r) * A_ + a0 + tx];
    }
    __syncthreads();
    #pragma unroll
    for (int i = 0; i < 4; ++i) {
        int r = ty4 * 4 + i;
        out[(size_t)(a0 + r) * H2_ + h0 + tx] = __float2bfloat16(tile[tx][r]);
    }
}

// T1[b*256+a] = attn_b[a] + sum_z Pz[z][6144+b][a]
__global__ __launch_bounds__(256)
void t1red_kernel(const float* __restrict__ Pz, const float* __restrict__ ab,
                  float* __restrict__ T1) {
    int i = blockIdx.x * 256 + threadIdx.x;       // 65536
    int b = i >> 8, a = i & 255;
    float v = ab[a];
    #pragma unroll
    for (int z = 0; z < ZSPL_; ++z)
        v += Pz[((size_t)z * MR_ + 6144 + b) * A_ + a];
    T1[i] = v;
}

// scores[q] = sum_a tanh(sum_z Pz[z][q][a] + T1[b,a]) * v[a],  q = s*256+b
__global__ __launch_bounds__(256)
void scores_kernel(const float* __restrict__ Pz, const float* __restrict__ T1,
                   const float* __restrict__ v, float* __restrict__ SC) {
    int wave = threadIdx.x >> 6, lane = threadIdx.x & 63;
    int q = blockIdx.x * 4 + wave;
    if (q >= BS_) return;
    int b = q & 255;
    float s = 0.f;
    #pragma unroll
    for (int a = lane; a < A_; a += 64) {
        float val = T1[b * A_ + a];
        #pragma unroll
        for (int z = 0; z < ZSPL_; ++z)
            val += Pz[((size_t)z * MR_ + q) * A_ + a];
        s += tanhf(val) * v[a];
    }
    #pragma unroll
    for (int off = 32; off; off >>= 1) s += __shfl_down(s, off, 64);
    if (lane == 0) SC[q] = s;
}

// weighted[b,h] = softmax_s(SC[:,b]) . enc_f32[:,b,h]
__global__ __launch_bounds__(256)
void weighted_f32_kernel(const float4* __restrict__ E4, const float* __restrict__ SC,
                         float4* __restrict__ WT4) {
    int g = blockIdx.x * 256 + threadIdx.x;            // B_*H_/4
    int b = g / (H_ / 4), c = g % (H_ / 4);
    float sc[S_];
    float mx = -1e30f;
    #pragma unroll
    for (int s = 0; s < S_; ++s) { sc[s] = SC[s * B_ + b]; mx = fmaxf(mx, sc[s]); }
    float sum = 0.f;
    #pragma unroll
    for (int s = 0; s < S_; ++s) { sc[s] = expf(sc[s] - mx); sum += sc[s]; }
    float inv = 1.f / sum;
    float4 acc = make_float4(0.f, 0.f, 0.f, 0.f);
    #pragma unroll
    for (int s = 0; s < S_; ++s) {
        float w = sc[s] * inv;
        float4 ev = E4[(size_t)(s * B_ + b) * (H_ / 4) + c];
        acc.x += w * ev.x; acc.y += w * ev.y;
        acc.z += w * ev.z; acc.w += w * ev.w;
    }
    WT4[(size_t)b * (H_ / 4) + c] = acc;
}

// CAT_T builder (y<4) + phase-B weight prep (y==4, grid-stride).
__global__ __launch_bounds__(256)
void catT_prepB_kernel(const float* __restrict__ inp, const float* __restrict__ WT,
                       const float* __restrict__ hid, __hip_bfloat16* __restrict__ CT,
                       const float* __restrict__ adj, const float* __restrict__ Wru,
                       const float* __restrict__ Wc, __hip_bfloat16* __restrict__ ADJ,
                       __hip_bfloat16* __restrict__ WRUT, __hip_bfloat16* __restrict__ WCT) {
    const int tid = threadIdx.x;
    if (blockIdx.y == 4) {
        for (int i = blockIdx.x * 256 + tid; i < 102400; i += 65536) {
            if (i < 65536) {
                int r = i >> 8, c = i & 255;
                ADJ[i] = __float2bfloat16((r < N_ && c < N_) ? adj[r * N_ + c] : 0.f);
            } else if (i < 90112) {
                int idx = i - 65536;
                int j = idx / FP_, f = idx % FP_;
                WRUT[idx] = __float2bfloat16(f < NF_ ? Wru[f * 128 + j] : 0.f);
            } else {
                int idx = i - 90112;
                int j = idx / FP_, f = idx % FP_;
                WCT[idx] = __float2bfloat16(f < NF_ ? Wc[f * 64 + j] : 0.f);
            }
        }
        return;
    }
    __shared__ float ww[64][65];
    __shared__ float wh[64][65];
    __shared__ float wi[64];
    const int b = blockIdx.x;
    const int k0 = blockIdx.y * 64;
    #pragma unroll
    for (int i = 0; i < 16; ++i) {
        int idx = tid + i * 256;
        int kn = idx >> 6, f = idx & 63;
        int k = k0 + kn;
        bool vld = (k < N_);
        ww[kn][f] = vld ? WT [(size_t)b * H_ + k * 64 + f] : 0.f;
        wh[kn][f] = vld ? hid[(size_t)b * H_ + k * 64 + f] : 0.f;
    }
    if (tid < 64) wi[tid] = (k0 + tid < N_) ? inp[b * N_ + k0 + tid] : 0.f;
    __syncthreads();
    #pragma unroll
    for (int i = 0; i < 6; ++i) {
        int cid = tid + i * 256;
        int f = cid >> 3, kk = (cid & 7) * 8;
        union { __hip_bfloat16 h[8]; bf16x8 v; } pk;
        #pragma unroll
        for (int j = 0; j < 8; ++j) {
            float x;
            if (f == 0)        x = wi[kk + j];
            else if (f <= 64)  x = ww[kk + j][f - 1];
            else if (f <= 128) x = wh[kk + j][f - 65];
            else               x = 0.f;
            pk.h[j] = __float2bfloat16(x);
        }
        *(bf16x8*)(CT + ((size_t)b * FP_ + f) * KP_ + k0 + kk) = pk.v;
    }
}

// RH_T builder: rows (b*64+u), cols k: r[k,b,u]*h[b,k,u], bf16
__global__ __launch_bounds__(256)
void rhT_kernel(const float* __restrict__ RU, const float* __restrict__ hid,
                __hip_bfloat16* __restrict__ RT) {
    __shared__ float rh[64][65];
    const int b = blockIdx.x, k0 = blockIdx.y * 64, tid = threadIdx.x;
    #pragma unroll
    for (int i = 0; i < 16; ++i) {
        int idx = tid + i * 256;
        int kn = idx >> 6, u = idx & 63;
        int k = k0 + kn;
        float v = 0.f;
        if (k < N_)
            v = RU[((size_t)k * 256 + b) * 128 + u] * hid[(size_t)b * H_ + k * 64 + u];
        rh[kn][u] = v;
    }
    __syncthreads();
    #pragma unroll
    for (int i = 0; i < 2; ++i) {
        int cid = tid + i * 256;
        int u = cid >> 3, kk = (cid & 7) * 8;
        union { __hip_bfloat16 h[8]; bf16x8 v; } pk;
        #pragma unroll
        for (int j = 0; j < 8; ++j) pk.h[j] = __float2bfloat16(rh[kk + j][u]);
        *(bf16x8*)(RT + ((size_t)b * 64 + u) * KP_ + k0 + kk) = pk.v;
    }
}

extern "C" void kernel_launch(void* const* d_in, const int* in_sizes, int n_in,
                              void* d_out, int out_size, void* d_ws, size_t ws_size,
                              hipStream_t stream) {
    const float* inp    = (const float*)d_in[0];
    const float* enc    = (const float*)d_in[1];
    const float* hid    = (const float*)d_in[2];
    const float* adj    = (const float*)d_in[3];
    const float* attn_W = (const float*)d_in[4];
    const float* attn_b = (const float*)d_in[5];
    const float* attn_v = (const float*)d_in[6];
    const float* W_ru   = (const float*)d_in[7];
    const float* b_ru   = (const float*)d_in[8];
    const float* W_c    = (const float*)d_in[9];
    const float* b_c    = (const float*)d_in[10];
    const float* proj_W = (const float*)d_in[11];
    const float* proj_b = (const float*)d_in[12];

    float* out0 = (float*)d_out;
    float* out2 = out0 + (size_t)B_ * N_;

    // Workspace (float offsets) — R8-validated region map kept.
    float* ws  = (float*)d_ws;
    float* T1  = ws;                      // 65536
    float* Pold= T1 + 65536;              // 1572864 (unused; layout stable)
    float* SC  = Pold + 1572864;          // 6144
    float* AW  = SC + 6144;               // 6144 (unused; layout stable)
    float* WT  = AW + 6144;               // 3391488
    float* BIG = WT + 3391488;            // off 5042176
    float* Pz  = BIG;                     // [0, 14745600)
    __hip_bfloat16* WT_BF  = (__hip_bfloat16*)(BIG + 40697856);
    __hip_bfloat16* CAT_T  = (__hip_bfloat16*)BIG;
    __hip_bfloat16* MB_BF  = (__hip_bfloat16*)(BIG + 6291456);
    __hip_bfloat16* RH_T   = (__hip_bfloat16*)(BIG + 12582912);
    float*          RU     = BIG + 14680064;
    __hip_bfloat16* ADJ_BF = (__hip_bfloat16*)(BIG + 21463040);
    __hip_bfloat16* WRUT   = (__hip_bfloat16*)(BIG + 21495808);
    __hip_bfloat16* WCT    = (__hip_bfloat16*)(BIG + 21508096);

    // --- prep: attn_W transpose ---
    transpose_cvt_kernel<<<dim3(H2_/32, A_/32), 256, 0, stream>>>(attn_W, WT_BF);

    // --- attention GEMM: dbuf, BN=128, 3 blocks/CU, partial stores ---
    gemm_enchid<<<dim3(2, 100, ZSPL_), 256, 0, stream>>>(
        enc, hid, WT_BF, Pz, 1472, 23);

    t1red_kernel<<<256, 256, 0, stream>>>(Pz, attn_b, T1);
    scores_kernel<<<BS_/4, 256, 0, stream>>>(Pz, T1, attn_v, SC);
    weighted_f32_kernel<<<(B_*(H_/4))/256, 256, 0, stream>>>(
        (const float4*)enc, SC, (float4*)WT);

    // --- phase B (Pz dead; CAT_T overlays it) ---
    catT_prepB_kernel<<<dim3(256, 5), 256, 0, stream>>>(
        inp, WT, hid, CAT_T, adj, W_ru, W_c, ADJ_BF, WRUT, WCT);

    mfma_gemm<64,128,2><<<dim3(384,4,1), 256, 0, stream>>>(
        ADJ_BF, KP_, CAT_T, KP_, MB_BF, 49152, 0, 4,
        nullptr, nullptr, nullptr, nullptr, nullptr, nullptr, nullptr, nullptr);

    mfma_gemm<64,64,4><<<dim3(2,828,1), 256, 0, stream>>>(
        MB_BF, FP_, WRUT, FP_, RU, 128, 0, 3,
        b_ru, nullptr, nullptr, nullptr, nullptr, nullptr, nullptr, nullptr);

    rhT_kernel<<<dim3(256,4), 256, 0, stream>>>(RU, hid, RH_T);

    mfma_gemm<64,128,3><<<dim3(128,4,1), 256, 0, stream>>>(
        ADJ_BF, KP_, RH_T, KP_, MB_BF, 0, 0, 4,
        nullptr, nullptr, nullptr, nullptr, nullptr, nullptr, nullptr, nullptr);

    // c-GEMM + GRU + FUSED projection -> out2 (newh) and out0
    mfma_gemm<64,64,5><<<dim3(1,828,1), 256, 0, stream>>>(
        MB_BF, FP_, WCT, FP_, out2, 0, 0, 3,
        b_c, RU, hid, WT, proj_W, proj_b, inp, out0);
}

// Round 20
// 264.709 us; speedup vs baseline: 1.0879x; 1.0879x over previous
//
#include <hip/hip_runtime.h>
#include <hip/hip_bf16.h>
#include <math.h>

// Problem constants
#define B_ 256
#define S_ 24
#define N_ 207
#define U_ 64
#define A_ 256
#define H_ (N_*U_)          // 13248
#define H2_ (2*H_)          // 26496
#define BS_ (B_*S_)         // 6144
#define NF_ 129             // 1 + 2U
#define FP_ 192             // padded feature width of MB rows
#define KP_ 256             // padded node count (K of adj GEMMs)
#define MR_ 6400            // unified attention rows: 6144 enc + 256 hid
#define ZSPL_ 9             // split-K partials

typedef __attribute__((ext_vector_type(8))) short bf16x8;
typedef __attribute__((ext_vector_type(4))) float f32x4;

#define GAS __attribute__((address_space(1)))
#define LAS __attribute__((address_space(3)))

static __device__ __forceinline__ void gload16(const __hip_bfloat16* g, void* lds) {
    __builtin_amdgcn_global_load_lds((const GAS uint32_t*)g, (LAS uint32_t*)lds, 16, 0, 0);
}

// ---------------------------------------------------------------------------
// bf16 MFMA GEMM template (R8-R16-validated core). C = A[M,K] @ BT[N,K]^T.
// EPI: 2 = bf16 store; 3 = bf16 remap (rh cols); 4 = sigmoid store;
//      5 = GRU epilogue + FUSED output projection (BN=64 required).
// ---------------------------------------------------------------------------
template<int BM, int BN, int EPI>
__global__ __launch_bounds__(256)
void mfma_gemm(const __hip_bfloat16* __restrict__ A, int lda,
               const __hip_bfloat16* __restrict__ BT, int ldb,
               void* __restrict__ Cv, int ldc,
               int kchunk, int niter,
               const float* __restrict__ ep0,
               const float* __restrict__ ep1,
               const float* __restrict__ ep2,
               const float* __restrict__ e_wt,
               const float* __restrict__ e_pw,
               const float* __restrict__ e_pb,
               const float* __restrict__ e_in,
               float* __restrict__ e_o0)
{
    constexpr int FM = BM / 32, FN = BN / 32;
    __shared__ __align__(128) char smem[(BM + BN) * 128];
    char* As = smem;
    char* Bs = smem + BM * 128;

    const int tid  = threadIdx.x;
    const int lane = tid & 63;
    const int wid  = tid >> 6;
    const int wr   = wid >> 1, wc = wid & 1;

    const int n0 = blockIdx.x * BN;
    const int m0 = blockIdx.y * BM;
    const long k0 = (long)blockIdx.z * kchunk;

    const int qk = lane >> 4;
    const int fr = lane & 15;
    const int sw = (lane & 7) << 4;

    f32x4 acc[FM][FN] = {};

    for (int it = 0; it < niter; ++it) {
        const long kb = k0 + (long)it * 64;
        #pragma unroll
        for (int p = 0; p < BM / 32; ++p) {
            const int chunk = p * 4 + wid;
            const int blk   = chunk * 64 + lane;
            const int r     = blk >> 3;
            const int klog  = ((blk & 7) << 4) ^ ((r & 7) << 4);
            gload16(A + (size_t)(m0 + r) * lda + kb + (klog >> 1), As + chunk * 1024);
        }
        #pragma unroll
        for (int p = 0; p < BN / 32; ++p) {
            const int chunk = p * 4 + wid;
            const int blk   = chunk * 64 + lane;
            const int r     = blk >> 3;
            const int klog  = ((blk & 7) << 4) ^ ((r & 7) << 4);
            gload16(BT + (size_t)(n0 + r) * ldb + kb + (klog >> 1), Bs + chunk * 1024);
        }
        __syncthreads();
        #pragma unroll
        for (int ks = 0; ks < 2; ++ks) {
            const int ko = ks * 64 + qk * 16;
            bf16x8 a[FM], b[FN];
            #pragma unroll
            for (int i = 0; i < FM; ++i)
                a[i] = *(const bf16x8*)(As + (wr * (BM/2) + i * 16 + fr) * 128 + (ko ^ sw));
            #pragma unroll
            for (int j = 0; j < FN; ++j)
                b[j] = *(const bf16x8*)(Bs + (wc * (BN/2) + j * 16 + fr) * 128 + (ko ^ sw));
            #pragma unroll
            for (int i = 0; i < FM; ++i)
                #pragma unroll
                for (int j = 0; j < FN; ++j)
                    acc[i][j] = __builtin_amdgcn_mfma_f32_16x16x32_bf16(a[i], b[j], acc[i][j], 0, 0, 0);
        }
        __syncthreads();
    }

    // EPI=5 projection reduction buffer (aliases LDS, dead after last sync)
    float* rsum = (float*)smem;
    if (EPI == 5) {
        if (tid < BM) rsum[tid] = 0.f;
        __syncthreads();
    }
    float tpart[FM][4];
    if (EPI == 5) {
        #pragma unroll
        for (int mi = 0; mi < FM; ++mi)
            #pragma unroll
            for (int q = 0; q < 4; ++q) tpart[mi][q] = 0.f;
    }

    // C/D layout: col=lane&15, row=(lane>>4)*4+reg  [m89-verified]
    #pragma unroll
    for (int mi = 0; mi < FM; ++mi)
        #pragma unroll
        for (int ni = 0; ni < FN; ++ni) {
            const int rbase = m0 + wr * (BM/2) + mi * 16 + qk * 4;
            const int col   = n0 + wc * (BN/2) + ni * 16 + fr;
            #pragma unroll
            for (int q = 0; q < 4; ++q) {
                const int row = rbase + q;
                const float v = acc[mi][ni][q];
                if (EPI == 2) {
                    ((__hip_bfloat16*)Cv)[(size_t)row * ldc + col] = __float2bfloat16(v);
                } else if (EPI == 3) {
                    const int bb = col >> 6, uu = col & 63;
                    ((__hip_bfloat16*)Cv)[((size_t)row * 256 + bb) * FP_ + 65 + uu] = __float2bfloat16(v);
                } else if (EPI == 4) {
                    float sv = v + ep0[col];
                    ((float*)Cv)[(size_t)row * ldc + col] = 1.f / (1.f + expf(-sv));
                } else { // EPI == 5
                    const int nn = row >> 8, bb = row & 255;
                    float cg = tanhf(v + ep0[col]);
                    float ug = ep1[(size_t)row * 128 + 64 + col];
                    const size_t hoff = (size_t)bb * H_ + nn * U_ + col;
                    float nh = ug * ep2[hoff] + (1.f - ug) * cg;
                    ((float*)Cv)[hoff] = nh;
                    tpart[mi][q] += nh * e_pw[col] + e_wt[hoff] * e_pw[64 + col];
                }
            }
        }

    if (EPI == 5) {
        #pragma unroll
        for (int mi = 0; mi < FM; ++mi)
            #pragma unroll
            for (int q = 0; q < 4; ++q) {
                float t = tpart[mi][q];
                #pragma unroll
                for (int off = 8; off; off >>= 1) t += __shfl_xor(t, off, 16);
                if (fr == 0) {
                    const int rloc = wr * (BM/2) + mi * 16 + qk * 4 + q;
                    atomicAdd(&rsum[rloc], t);   // LDS atomic — cheap
                }
            }
        __syncthreads();
        if (tid < BM) {
            const int row = m0 + tid;
            const int nn = row >> 8, bb = row & 255;
            e_o0[bb * N_ + nn] = rsum[tid] + e_in[bb * N_ + nn] * e_pw[128] + e_pb[0];
        }
    }
}

// ---------------------------------------------------------------------------
// Fused attention GEMM — R16-validated double-buffered form (best measured).
// BM=64/BN=256, split-K z=9, partial stores; B staged via gload_lds
// (coalesced — R17's direct-from-L2 B read was a 16-way gather, -100us;
// R19's BN=128 occupancy variant re-staged A twice, -22us).
// ---------------------------------------------------------------------------
__global__ __launch_bounds__(256)
void gemm_enchid(const float* __restrict__ Aenc,
                 const float* __restrict__ Ahid,
                 const __hip_bfloat16* __restrict__ WTBF,
                 float* __restrict__ Pz,
                 int kchunk, int niter)
{
    __shared__ __align__(128) char smem[2 * (64 + 256) * 128];   // 80 KB

    const int tid  = threadIdx.x;
    const int lane = tid & 63;
    const int wid  = tid >> 6;
    const int wr   = wid >> 1, wc = wid & 1;

    const bool isH = (blockIdx.y >= 96);
    const float* A = isH ? Ahid : Aenc;
    const int lm0  = (isH ? (blockIdx.y - 96) : blockIdx.y) * 64;
    const int gm0  = (isH ? 6144 : 0) + lm0;
    const __hip_bfloat16* BT = WTBF + (isH ? 0 : H_);

    const long k0 = (long)blockIdx.z * kchunk;

    const int qk = lane >> 4;
    const int fr = lane & 15;
    const int sw = (lane & 7) << 4;

    int arow[2], akc[2];
    #pragma unroll
    for (int h = 0; h < 2; ++h) {
        const int c = h * 256 + tid;
        arow[h] = c >> 3;
        akc[h]  = c & 7;
    }

    f32x4 acc[2][8] = {};
    float4 pfx[2], pfy[2];

    // ---- prologue: stage tile 0 into buf0 ----
    {
        const long kb = k0;
        #pragma unroll
        for (int p = 0; p < 8; ++p) {
            const int chunk = p * 4 + wid;
            const int blk   = chunk * 64 + lane;
            const int r     = blk >> 3;
            const int klog  = ((blk & 7) << 4) ^ ((r & 7) << 4);
            gload16(BT + (size_t)r * H2_ + kb + (klog >> 1), smem + 8192 + chunk * 1024);
        }
        #pragma unroll
        for (int h = 0; h < 2; ++h) {
            const float* src = A + (size_t)(lm0 + arow[h]) * H_ + kb + akc[h] * 8;
            pfx[h] = *(const float4*)(src);
            pfy[h] = *(const float4*)(src + 4);
        }
        #pragma unroll
        for (int h = 0; h < 2; ++h) {
            union { __hip_bfloat16 hh[8]; int4 u; } pk;
            pk.hh[0] = __float2bfloat16(pfx[h].x); pk.hh[1] = __float2bfloat16(pfx[h].y);
            pk.hh[2] = __float2bfloat16(pfx[h].z); pk.hh[3] = __float2bfloat16(pfx[h].w);
            pk.hh[4] = __float2bfloat16(pfy[h].x); pk.hh[5] = __float2bfloat16(pfy[h].y);
            pk.hh[6] = __float2bfloat16(pfy[h].z); pk.hh[7] = __float2bfloat16(pfy[h].w);
            *(int4*)(smem + arow[h] * 128 + ((akc[h] << 4) ^ ((arow[h] & 7) << 4))) = pk.u;
        }
        __syncthreads();
    }

    int cur = 0;
    for (int it = 0; it < niter; ++it) {
        char* curbuf = smem + cur * 40960;
        char* altbuf = smem + (cur ^ 1) * 40960;
        const bool pf = (it + 1 < niter);
        const long kbn = k0 + (long)(it + 1) * 64;

        if (pf) {
            #pragma unroll
            for (int p = 0; p < 8; ++p) {
                const int chunk = p * 4 + wid;
                const int blk   = chunk * 64 + lane;
                const int r     = blk >> 3;
                const int klog  = ((blk & 7) << 4) ^ ((r & 7) << 4);
                gload16(BT + (size_t)r * H2_ + kbn + (klog >> 1), altbuf + 8192 + chunk * 1024);
            }
            #pragma unroll
            for (int h = 0; h < 2; ++h) {
                const float* src = A + (size_t)(lm0 + arow[h]) * H_ + kbn + akc[h] * 8;
                pfx[h] = *(const float4*)(src);
                pfy[h] = *(const float4*)(src + 4);
            }
        }

        #pragma unroll
        for (int ks = 0; ks < 2; ++ks) {
            const int ko = ks * 64 + qk * 16;
            bf16x8 a[2], b[8];
            #pragma unroll
            for (int i = 0; i < 2; ++i)
                a[i] = *(const bf16x8*)(curbuf + (wr * 32 + i * 16 + fr) * 128 + (ko ^ sw));
            #pragma unroll
            for (int j = 0; j < 8; ++j)
                b[j] = *(const bf16x8*)(curbuf + 8192 + (wc * 128 + j * 16 + fr) * 128 + (ko ^ sw));
            #pragma unroll
            for (int i = 0; i < 2; ++i)
                #pragma unroll
                for (int j = 0; j < 8; ++j)
                    acc[i][j] = __builtin_amdgcn_mfma_f32_16x16x32_bf16(a[i], b[j], acc[i][j], 0, 0, 0);
        }

        if (pf) {
            #pragma unroll
            for (int h = 0; h < 2; ++h) {
                union { __hip_bfloat16 hh[8]; int4 u; } pk;
                pk.hh[0] = __float2bfloat16(pfx[h].x); pk.hh[1] = __float2bfloat16(pfx[h].y);
                pk.hh[2] = __float2bfloat16(pfx[h].z); pk.hh[3] = __float2bfloat16(pfx[h].w);
                pk.hh[4] = __float2bfloat16(pfy[h].x); pk.hh[5] = __float2bfloat16(pfy[h].y);
                pk.hh[6] = __float2bfloat16(pfy[h].z); pk.hh[7] = __float2bfloat16(pfy[h].w);
                *(int4*)(altbuf + arow[h] * 128 + ((akc[h] << 4) ^ ((arow[h] & 7) << 4))) = pk.u;
            }
        }
        __syncthreads();
        cur ^= 1;
    }

    float* Pzs = Pz + (size_t)blockIdx.z * MR_ * A_;
    #pragma unroll
    for (int mi = 0; mi < 2; ++mi)
        #pragma unroll
        for (int ni = 0; ni < 8; ++ni) {
            const int rbase = gm0 + wr * 32 + mi * 16 + qk * 4;
            const int col   = wc * 128 + ni * 16 + fr;
            #pragma unroll
            for (int q = 0; q < 4; ++q)
                Pzs[(size_t)(rbase + q) * A_ + col] = acc[mi][ni][q];
        }
}

// attn_W (2H, 256) fp32 -> WT_BF (256, 2H) bf16, 32x32 LDS tiles
__global__ __launch_bounds__(256)
void transpose_cvt_kernel(const float* __restrict__ in, __hip_bfloat16* __restrict__ out) {
    __shared__ float tile[32][33];
    const int h0 = blockIdx.x * 32, a0 = blockIdx.y * 32;
    const int tx = threadIdx.x & 31, ty4 = threadIdx.x >> 5;
    #pragma unroll
    for (int i = 0; i < 4; ++i) {
        int r = ty4 * 4 + i;
        tile[r][tx] = in[(size_t)(h0 + r) * A_ + a0 + tx];
    }
    __syncthreads();
    #pragma unroll
    for (int i = 0; i < 4; ++i) {
        int r = ty4 * 4 + i;
        out[(size_t)(a0 + r) * H2_ + h0 + tx] = __float2bfloat16(tile[tx][r]);
    }
}

// T1[b*256+a] = attn_b[a] + sum_z Pz[z][6144+b][a]
__global__ __launch_bounds__(256)
void t1red_kernel(const float* __restrict__ Pz, const float* __restrict__ ab,
                  float* __restrict__ T1) {
    int i = blockIdx.x * 256 + threadIdx.x;       // 65536
    int b = i >> 8, a = i & 255;
    float v = ab[a];
    #pragma unroll
    for (int z = 0; z < ZSPL_; ++z)
        v += Pz[((size_t)z * MR_ + 6144 + b) * A_ + a];
    T1[i] = v;
}

// scores[q] = sum_a tanh(sum_z Pz[z][q][a] + T1[b,a]) * v[a],  q = s*256+b
__global__ __launch_bounds__(256)
void scores_kernel(const float* __restrict__ Pz, const float* __restrict__ T1,
                   const float* __restrict__ v, float* __restrict__ SC) {
    int wave = threadIdx.x >> 6, lane = threadIdx.x & 63;
    int q = blockIdx.x * 4 + wave;
    if (q >= BS_) return;
    int b = q & 255;
    float s = 0.f;
    #pragma unroll
    for (int a = lane; a < A_; a += 64) {
        float val = T1[b * A_ + a];
        #pragma unroll
        for (int z = 0; z < ZSPL_; ++z)
            val += Pz[((size_t)z * MR_ + q) * A_ + a];
        s += tanhf(val) * v[a];
    }
    #pragma unroll
    for (int off = 32; off; off >>= 1) s += __shfl_down(s, off, 64);
    if (lane == 0) SC[q] = s;
}

// weighted[b,h] = softmax_s(SC[:,b]) . enc_f32[:,b,h]
__global__ __launch_bounds__(256)
void weighted_f32_kernel(const float4* __restrict__ E4, const float* __restrict__ SC,
                         float4* __restrict__ WT4) {
    int g = blockIdx.x * 256 + threadIdx.x;            // B_*H_/4
    int b = g / (H_ / 4), c = g % (H_ / 4);
    float sc[S_];
    float mx = -1e30f;
    #pragma unroll
    for (int s = 0; s < S_; ++s) { sc[s] = SC[s * B_ + b]; mx = fmaxf(mx, sc[s]); }
    float sum = 0.f;
    #pragma unroll
    for (int s = 0; s < S_; ++s) { sc[s] = expf(sc[s] - mx); sum += sc[s]; }
    float inv = 1.f / sum;
    float4 acc = make_float4(0.f, 0.f, 0.f, 0.f);
    #pragma unroll
    for (int s = 0; s < S_; ++s) {
        float w = sc[s] * inv;
        float4 ev = E4[(size_t)(s * B_ + b) * (H_ / 4) + c];
        acc.x += w * ev.x; acc.y += w * ev.y;
        acc.z += w * ev.z; acc.w += w * ev.w;
    }
    WT4[(size_t)b * (H_ / 4) + c] = acc;
}

// CAT_T builder (y<4) + phase-B weight prep (y==4, grid-stride).
__global__ __launch_bounds__(256)
void catT_prepB_kernel(const float* __restrict__ inp, const float* __restrict__ WT,
                       const float* __restrict__ hid, __hip_bfloat16* __restrict__ CT,
                       const float* __restrict__ adj, const float* __restrict__ Wru,
                       const float* __restrict__ Wc, __hip_bfloat16* __restrict__ ADJ,
                       __hip_bfloat16* __restrict__ WRUT, __hip_bfloat16* __restrict__ WCT) {
    const int tid = threadIdx.x;
    if (blockIdx.y == 4) {
        for (int i = blockIdx.x * 256 + tid; i < 102400; i += 65536) {
            if (i < 65536) {
                int r = i >> 8, c = i & 255;
                ADJ[i] = __float2bfloat16((r < N_ && c < N_) ? adj[r * N_ + c] : 0.f);
            } else if (i < 90112) {
                int idx = i - 65536;
                int j = idx / FP_, f = idx % FP_;
                WRUT[idx] = __float2bfloat16(f < NF_ ? Wru[f * 128 + j] : 0.f);
            } else {
                int idx = i - 90112;
                int j = idx / FP_, f = idx % FP_;
                WCT[idx] = __float2bfloat16(f < NF_ ? Wc[f * 64 + j] : 0.f);
            }
        }
        return;
    }
    __shared__ float ww[64][65];
    __shared__ float wh[64][65];
    __shared__ float wi[64];
    const int b = blockIdx.x;
    const int k0 = blockIdx.y * 64;
    #pragma unroll
    for (int i = 0; i < 16; ++i) {
        int idx = tid + i * 256;
        int kn = idx >> 6, f = idx & 63;
        int k = k0 + kn;
        bool vld = (k < N_);
        ww[kn][f] = vld ? WT [(size_t)b * H_ + k * 64 + f] : 0.f;
        wh[kn][f] = vld ? hid[(size_t)b * H_ + k * 64 + f] : 0.f;
    }
    if (tid < 64) wi[tid] = (k0 + tid < N_) ? inp[b * N_ + k0 + tid] : 0.f;
    __syncthreads();
    #pragma unroll
    for (int i = 0; i < 6; ++i) {
        int cid = tid + i * 256;
        int f = cid >> 3, kk = (cid & 7) * 8;
        union { __hip_bfloat16 h[8]; bf16x8 v; } pk;
        #pragma unroll
        for (int j = 0; j < 8; ++j) {
            float x;
            if (f == 0)        x = wi[kk + j];
            else if (f <= 64)  x = ww[kk + j][f - 1];
            else if (f <= 128) x = wh[kk + j][f - 65];
            else               x = 0.f;
            pk.h[j] = __float2bfloat16(x);
        }
        *(bf16x8*)(CT + ((size_t)b * FP_ + f) * KP_ + k0 + kk) = pk.v;
    }
}

// RH_T builder: rows (b*64+u), cols k: r[k,b,u]*h[b,k,u], bf16
__global__ __launch_bounds__(256)
void rhT_kernel(const float* __restrict__ RU, const float* __restrict__ hid,
                __hip_bfloat16* __restrict__ RT) {
    __shared__ float rh[64][65];
    const int b = blockIdx.x, k0 = blockIdx.y * 64, tid = threadIdx.x;
    #pragma unroll
    for (int i = 0; i < 16; ++i) {
        int idx = tid + i * 256;
        int kn = idx >> 6, u = idx & 63;
        int k = k0 + kn;
        float v = 0.f;
        if (k < N_)
            v = RU[((size_t)k * 256 + b) * 128 + u] * hid[(size_t)b * H_ + k * 64 + u];
        rh[kn][u] = v;
    }
    __syncthreads();
    #pragma unroll
    for (int i = 0; i < 2; ++i) {
        int cid = tid + i * 256;
        int u = cid >> 3, kk = (cid & 7) * 8;
        union { __hip_bfloat16 h[8]; bf16x8 v; } pk;
        #pragma unroll
        for (int j = 0; j < 8; ++j) pk.h[j] = __float2bfloat16(rh[kk + j][u]);
        *(bf16x8*)(RT + ((size_t)b * 64 + u) * KP_ + k0 + kk) = pk.v;
    }
}

extern "C" void kernel_launch(void* const* d_in, const int* in_sizes, int n_in,
                              void* d_out, int out_size, void* d_ws, size_t ws_size,
                              hipStream_t stream) {
    const float* inp    = (const float*)d_in[0];
    const float* enc    = (const float*)d_in[1];
    const float* hid    = (const float*)d_in[2];
    const float* adj    = (const float*)d_in[3];
    const float* attn_W = (const float*)d_in[4];
    const float* attn_b = (const float*)d_in[5];
    const float* attn_v = (const float*)d_in[6];
    const float* W_ru   = (const float*)d_in[7];
    const float* b_ru   = (const float*)d_in[8];
    const float* W_c    = (const float*)d_in[9];
    const float* b_c    = (const float*)d_in[10];
    const float* proj_W = (const float*)d_in[11];
    const float* proj_b = (const float*)d_in[12];

    float* out0 = (float*)d_out;
    float* out2 = out0 + (size_t)B_ * N_;

    // Workspace (float offsets) — R8-validated region map kept.
    float* ws  = (float*)d_ws;
    float* T1  = ws;                      // 65536
    float* Pold= T1 + 65536;              // 1572864 (unused; layout stable)
    float* SC  = Pold + 1572864;          // 6144
    float* AW  = SC + 6144;               // 6144 (unused; layout stable)
    float* WT  = AW + 6144;               // 3391488
    float* BIG = WT + 3391488;            // off 5042176
    float* Pz  = BIG;                     // [0, 14745600)
    __hip_bfloat16* WT_BF  = (__hip_bfloat16*)(BIG + 40697856);
    __hip_bfloat16* CAT_T  = (__hip_bfloat16*)BIG;
    __hip_bfloat16* MB_BF  = (__hip_bfloat16*)(BIG + 6291456);
    __hip_bfloat16* RH_T   = (__hip_bfloat16*)(BIG + 12582912);
    float*          RU     = BIG + 14680064;
    __hip_bfloat16* ADJ_BF = (__hip_bfloat16*)(BIG + 21463040);
    __hip_bfloat16* WRUT   = (__hip_bfloat16*)(BIG + 21495808);
    __hip_bfloat16* WCT    = (__hip_bfloat16*)(BIG + 21508096);

    // --- prep: attn_W transpose ---
    transpose_cvt_kernel<<<dim3(H2_/32, A_/32), 256, 0, stream>>>(attn_W, WT_BF);

    // --- attention GEMM: R16 double-buffered form, partial stores ---
    gemm_enchid<<<dim3(1, 100, ZSPL_), 256, 0, stream>>>(
        enc, hid, WT_BF, Pz, 1472, 23);

    t1red_kernel<<<256, 256, 0, stream>>>(Pz, attn_b, T1);
    scores_kernel<<<BS_/4, 256, 0, stream>>>(Pz, T1, attn_v, SC);
    weighted_f32_kernel<<<(B_*(H_/4))/256, 256, 0, stream>>>(
        (const float4*)enc, SC, (float4*)WT);

    // --- phase B (Pz dead; CAT_T overlays it) ---
    catT_prepB_kernel<<<dim3(256, 5), 256, 0, stream>>>(
        inp, WT, hid, CAT_T, adj, W_ru, W_c, ADJ_BF, WRUT, WCT);

    mfma_gemm<64,64,2><<<dim3(768,4,1), 256, 0, stream>>>(
        ADJ_BF, KP_, CAT_T, KP_, MB_BF, 49152, 0, 4,
        nullptr, nullptr, nullptr, nullptr, nullptr, nullptr, nullptr, nullptr);

    mfma_gemm<64,64,4><<<dim3(2,828,1), 256, 0, stream>>>(
        MB_BF, FP_, WRUT, FP_, RU, 128, 0, 3,
        b_ru, nullptr, nullptr, nullptr, nullptr, nullptr, nullptr, nullptr);

    rhT_kernel<<<dim3(256,4), 256, 0, stream>>>(RU, hid, RH_T);

    mfma_gemm<64,64,3><<<dim3(256,4,1), 256, 0, stream>>>(
        ADJ_BF, KP_, RH_T, KP_, MB_BF, 0, 0, 4,
        nullptr, nullptr, nullptr, nullptr, nullptr, nullptr, nullptr, nullptr);

    // c-GEMM + GRU + FUSED projection -> out2 (newh) and out0
    mfma_gemm<64,64,5><<<dim3(1,828,1), 256, 0, stream>>>(
        MB_BF, FP_, WCT, FP_, out2, 0, 0, 3,
        b_c, RU, hid, WT, proj_W, proj_b, inp, out0);
}